// Round 4
// baseline (866.213 us; speedup 1.0000x reference)
//
#include <hip/hip_runtime.h>
#include <hip/hip_bf16.h>

typedef __bf16 b8v __attribute__((ext_vector_type(8)));
typedef float  f4v __attribute__((ext_vector_type(4)));
typedef unsigned long long ull;

#define AS3(p)  ((__attribute__((address_space(3))) void*)(p))
#define AS1C(p) ((const __attribute__((address_space(1))) void*)(p))

// ============================================================================
// GEMM: C[M,N] = A[M,K] @ Bt[N,K]^T   (A,Bt bf16 K-contig rows, fp32 acc)
// 128x128 tile, BK=32, 256 threads (2x2 waves of 64x64), mfma_f32_16x16x32_bf16
// Bt batch offset = (z>>3)*sBg + (z&7)*sBb; Bt row stride ldB (>= K window).
// ORIENT 0: swapped-operand MFMA -> lane holds 4 CONSECUTIVE COLUMNS of C
//           (row = lane&15) -> packed 8B bf16 / 16B fp32 stores, row-major C.
// ORIENT 1: normal MFMA -> lane holds 4 consecutive ROWS (col = lane&15)
//           -> writes C^T row-major [N][M] with packed stores (fused transpose).
// EPI: 0 none, 1 relu, 2 bias+gelu (bias by z&1), 3 sigmoid-gate (reads gcat,
//      adds bias0, writes fp32 out = s*g1+(1-s)*g2).  OBF: 1 bf16 out, 0 fp32.
// ============================================================================
template<int EPI, int OBF, int ORIENT>
__global__ __launch_bounds__(256) void gemm_bt(
    const __hip_bfloat16* __restrict__ A,  long long sA,
    const __hip_bfloat16* __restrict__ Bt, long long sBg, long long sBb, int ldB,
    void* __restrict__ Cv, long long sC, int ldC,
    const float* __restrict__ bias0, const float* __restrict__ bias1,
    const __hip_bfloat16* __restrict__ gcat, int K)
{
  const int bz = blockIdx.z;
  A  += (long long)bz * sA;
  Bt += (long long)(bz >> 3) * sBg + (long long)(bz & 7) * sBb;
  const float* __restrict__ bias = (bz & 1) ? bias1 : bias0;

  __shared__ __hip_bfloat16 As[128 * 32];
  __shared__ __hip_bfloat16 Bs[128 * 32];

  const int tid  = threadIdx.x;
  const int lane = tid & 63;
  const int wave = tid >> 6;

  const long long m0 = (long long)blockIdx.x * 128;
  const long long n0 = (long long)blockIdx.y * 128;

  // staging: thread t -> tile row r = t>>2, LDS slot t&3 holds global k-cell
  // kc = (t&3)^((r>>2)&3)  (XOR swizzle, cancelled on read)
  const int r  = tid >> 2;
  const int kc = (tid & 3) ^ ((r >> 2) & 3);
  const __hip_bfloat16* aSrc = A  + (m0 + r) * (long long)K   + kc * 8;
  const __hip_bfloat16* bSrc = Bt + (n0 + r) * (long long)ldB + kc * 8;

  const int wm = (wave & 1) * 64;
  const int wn = (wave >> 1) * 64;
  const int lm = lane & 15;   // m (A-frag) / n (B-frag) within 16x16 tile
  const int kq = lane >> 4;   // k quad (0..3), 8 elements each

  const int sw   = (lm >> 2) & 3;           // read-side unswizzle
  const int aOff = (wm + lm) * 32 + (kq ^ sw) * 8;
  const int bOff = (wn + lm) * 32 + (kq ^ sw) * 8;

  f4v acc[4][4];
  const f4v fzero = {0.0f, 0.0f, 0.0f, 0.0f};
#pragma unroll
  for (int i = 0; i < 4; i++)
#pragma unroll
    for (int j = 0; j < 4; j++) acc[i][j] = fzero;

  for (int k0 = 0; k0 < K; k0 += 32) {
    __builtin_amdgcn_global_load_lds(AS1C(aSrc),                AS3(As + tid * 8),        16, 0, 0);
    __builtin_amdgcn_global_load_lds(AS1C(aSrc + 64LL * K),     AS3(As + 2048 + tid * 8), 16, 0, 0);
    __builtin_amdgcn_global_load_lds(AS1C(bSrc),                AS3(Bs + tid * 8),        16, 0, 0);
    __builtin_amdgcn_global_load_lds(AS1C(bSrc + 64LL * ldB),   AS3(Bs + 2048 + tid * 8), 16, 0, 0);
    __syncthreads();

    b8v af[4], bf[4];
#pragma unroll
    for (int i = 0; i < 4; i++) af[i] = *(const b8v*)(As + aOff + i * 16 * 32);
#pragma unroll
    for (int j = 0; j < 4; j++) bf[j] = *(const b8v*)(Bs + bOff + j * 16 * 32);

#pragma unroll
    for (int i = 0; i < 4; i++)
#pragma unroll
      for (int j = 0; j < 4; j++) {
        if constexpr (ORIENT == 0)
          acc[i][j] = __builtin_amdgcn_mfma_f32_16x16x32_bf16(bf[j], af[i], acc[i][j], 0, 0, 0);
        else
          acc[i][j] = __builtin_amdgcn_mfma_f32_16x16x32_bf16(af[i], bf[j], acc[i][j], 0, 0, 0);
      }

    __syncthreads();
    aSrc += 32; bSrc += 32;
  }

  char* Cb = (char*)Cv;

#pragma unroll
  for (int i = 0; i < 4; i++) {
#pragma unroll
    for (int j = 0; j < 4; j++) {
      float v[4];
#pragma unroll
      for (int rg = 0; rg < 4; rg++) v[rg] = acc[i][j][rg];

      if constexpr (ORIENT == 0) {
        // lane: C row = m0+wm+i*16+lm ; cols = n0+wn+j*16+kq*4 + {0..3}
        const long long row  = m0 + wm + i * 16 + lm;
        const int       colb = (int)n0 + wn + j * 16 + kq * 4;
        if constexpr (EPI == 1) {
#pragma unroll
          for (int rg = 0; rg < 4; rg++) v[rg] = fmaxf(v[rg], 0.0f);
        }
        if constexpr (EPI == 2) {
          const float4 b4 = *(const float4*)(bias + colb);
          const float* bb = (const float*)&b4;
#pragma unroll
          for (int rg = 0; rg < 4; rg++) {
            float x = v[rg] + bb[rg];
            v[rg] = 0.5f * x * (1.0f + erff(x * 0.70710678118654752f));
          }
        }
        const long long base = bz * sC + row * (long long)ldC + colb;
        if constexpr (EPI == 3) {
          const float4 b4 = *(const float4*)(bias0 + colb);
          const float* bb = (const float*)&b4;
          union { __hip_bfloat16 h[4]; ull u; } g1, g2;
          g1.u = *(const ull*)(gcat + row * 1536 + colb);
          g2.u = *(const ull*)(gcat + row * 1536 + 768 + colb);
          float o[4];
#pragma unroll
          for (int rg = 0; rg < 4; rg++) {
            const float s = 1.0f / (1.0f + expf(-(v[rg] + bb[rg])));
            o[rg] = s * __bfloat162float(g1.h[rg]) +
                    (1.0f - s) * __bfloat162float(g2.h[rg]);
          }
          *(float4*)(Cb + base * 4) = *(const float4*)o;
        } else if constexpr (OBF) {
          union { __hip_bfloat16 h[4]; ull u; } P;
#pragma unroll
          for (int rg = 0; rg < 4; rg++) P.h[rg] = __float2bfloat16(v[rg]);
          *(ull*)(Cb + base * 2) = P.u;
        } else {
          *(float4*)(Cb + base * 4) = *(const float4*)v;
        }
      } else {
        // lane: C col(n) = n0+wn+j*16+lm ; rows(m) = m0+wm+i*16+kq*4 + {0..3}
        const long long crow = n0 + wn + j * 16 + lm;          // row of C^T
        const long long mb   = m0 + wm + i * 16 + kq * 4;
        if constexpr (EPI == 1) {
#pragma unroll
          for (int rg = 0; rg < 4; rg++) v[rg] = fmaxf(v[rg], 0.0f);
        }
        const long long base = bz * sC + crow * (long long)ldC + mb;
        if constexpr (OBF) {
          union { __hip_bfloat16 h[4]; ull u; } P;
#pragma unroll
          for (int rg = 0; rg < 4; rg++) P.h[rg] = __float2bfloat16(v[rg]);
          *(ull*)(Cb + base * 2) = P.u;
        } else {
          *(float4*)(Cb + base * 4) = *(const float4*)v;
        }
      }
    }
  }
}

// ============================================================================
// adj row-sums -> dinv = 1/sqrt(rowsum).  One wave per row. 16384 rows total.
// ============================================================================
__global__ __launch_bounds__(256) void rowsum_dinv(const float* __restrict__ g,
                                                   float* __restrict__ dinv)
{
  const int wave = threadIdx.x >> 6, lane = threadIdx.x & 63;
  const long long row = (long long)blockIdx.x * 4 + wave;   // [0, 16384)
  const float4* p = (const float4*)(g + row * 1024);
  float s = 0.0f;
#pragma unroll
  for (int k = 0; k < 4; k++) {
    float4 v = p[lane + k * 64];
    s += v.x + v.y + v.z + v.w;
  }
#pragma unroll
  for (int o = 32; o > 0; o >>= 1) s += __shfl_down(s, o);
  if (lane == 0) dinv[row] = 1.0f / sqrtf(s);
}

// ============================================================================
// adj_bf16[g][b][i][j] = graphs[b][g][i][j] * dinv[i] * dinv[j]  (graph-major)
// ============================================================================
__global__ __launch_bounds__(256) void scale_adj(const float* __restrict__ g,
                                                 const float* __restrict__ dinv,
                                                 __hip_bfloat16* __restrict__ out)
{
  const long long t = (long long)blockIdx.x * 256 + threadIdx.x; // quad index
  const long long e = t * 4;
  const int m = (int)(e >> 20);          // b*2+graph (input order)
  const int i = (int)((e >> 10) & 1023);
  const int j = (int)(e & 1023);
  const float4 v  = *(const float4*)(g + e);
  const float  di = dinv[m * 1024 + i];
  const float4 dj = *(const float4*)(dinv + m * 1024 + j);
  const int om = (m & 1) * 8 + (m >> 1); // z = graph*8 + b
  union { __hip_bfloat16 h[4]; ull u; } r;
  r.h[0] = __float2bfloat16(v.x * di * dj.x);
  r.h[1] = __float2bfloat16(v.y * di * dj.y);
  r.h[2] = __float2bfloat16(v.z * di * dj.z);
  r.h[3] = __float2bfloat16(v.w * di * dj.w);
  *(ull*)(out + ((long long)om << 20) + (long long)i * 1024 + j) = r.u;
}

// ============================================================================
// transpose + convert to bf16: out[C,R] = in[R,C], batched via grid.z
// ============================================================================
template<typename TIN>
__global__ void transpose_conv(const TIN* __restrict__ in, __hip_bfloat16* __restrict__ out,
                               int R, int C, long long sIn, long long sOut)
{
  __shared__ __hip_bfloat16 tile[32][33];
  in  += (long long)blockIdx.z * sIn;
  out += (long long)blockIdx.z * sOut;
  const int c0 = blockIdx.x * 32, r0 = blockIdx.y * 32;
  const int tx = threadIdx.x, ty = threadIdx.y;
#pragma unroll
  for (int i = 0; i < 32; i += 8)
    tile[ty + i][tx] = __float2bfloat16((float)in[(long long)(r0 + ty + i) * C + c0 + tx]);
  __syncthreads();
#pragma unroll
  for (int i = 0; i < 32; i += 8)
    out[(long long)(c0 + ty + i) * R + r0 + tx] = tile[tx][ty + i];
}

// ============================================================================
// residual + LayerNorm for BOTH graphs: rows [0,16384), g = row>>13.
// y = LN(nodes + V + col_b) -> bf16 slice of Gcat[r, g*768 : +768].  V bf16.
// ============================================================================
__global__ __launch_bounds__(256) void ln_residual2(
    const float* __restrict__ nodes, const __hip_bfloat16* __restrict__ V,
    const float* __restrict__ colb0, const float* __restrict__ colb1,
    const float* __restrict__ lng0,  const float* __restrict__ lng1,
    const float* __restrict__ lnb0,  const float* __restrict__ lnb1,
    __hip_bfloat16* __restrict__ gcat)
{
  const long long row = blockIdx.x;          // 0..16383
  const int g = (int)(row >> 13);
  const long long rr = row & 8191;           // node row
  const float* __restrict__ colb = g ? colb1 : colb0;
  const float* __restrict__ lng  = g ? lng1  : lng0;
  const float* __restrict__ lnb  = g ? lnb1  : lnb0;
  const int t = threadIdx.x;
  const long long nbase = rr * 768;
  const long long vbase = row * 768;
  float x[3]; float s = 0.0f, ss = 0.0f;
#pragma unroll
  for (int i = 0; i < 3; i++) {
    const int c = t + i * 256;
    const float v = nodes[nbase + c] + __bfloat162float(V[vbase + c]) + colb[c];
    x[i] = v; s += v; ss += v * v;
  }
  __shared__ float red[8];
#pragma unroll
  for (int o = 32; o > 0; o >>= 1) { s += __shfl_down(s, o); ss += __shfl_down(ss, o); }
  const int wave = t >> 6, lane = t & 63;
  if (lane == 0) { red[wave] = s; red[4 + wave] = ss; }
  __syncthreads();
  if (t == 0) {
    red[0] = red[0] + red[1] + red[2] + red[3];
    red[4] = red[4] + red[5] + red[6] + red[7];
  }
  __syncthreads();
  const float mu  = red[0] * (1.0f / 768.0f);
  float var = red[4] * (1.0f / 768.0f) - mu * mu;
  var = fmaxf(var, 0.0f);
  const float rs = rsqrtf(var + 1e-12f);
#pragma unroll
  for (int i = 0; i < 3; i++) {
    const int c = t + i * 256;
    const float y = (x[i] - mu) * rs * lng[c] + lnb[c];
    gcat[rr * 1536 + g * 768 + c] = __float2bfloat16(y);
  }
}

// ============================================================================
// WeffT[n][k] (bf16, [768,1536]): folded gate weight
//   k<768 : (Wa+Wc+Wd)[k][n];  k>=768: (Wb+Wc-Wd)[k-768][n]
// ============================================================================
__global__ __launch_bounds__(256) void build_wefft(const float* __restrict__ gw,
                                                   __hip_bfloat16* __restrict__ wt)
{
  const int idx = blockIdx.x * 256 + threadIdx.x;  // 768*1536, exact
  const int n = idx / 1536, k = idx % 1536;
  float v;
  if (k < 768) v = gw[k * 768 + n] + gw[(1536 + k) * 768 + n] + gw[(2304 + k) * 768 + n];
  else {
    const int kk = k - 768;
    v = gw[(768 + kk) * 768 + n] + gw[(1536 + kk) * 768 + n] - gw[(2304 + kk) * 768 + n];
  }
  wt[idx] = __float2bfloat16(v);
}

// ============================================================================
extern "C" void kernel_launch(void* const* d_in, const int* in_sizes, int n_in,
                              void* d_out, int out_size, void* d_ws, size_t ws_size,
                              hipStream_t stream)
{
  const float* nodes  = (const float*)d_in[0];
  const float* graphs = (const float*)d_in[1];
  const float* gcn_w1[2] = { (const float*)d_in[2], (const float*)d_in[4] };
  const float* gcn_w2[2] = { (const float*)d_in[3], (const float*)d_in[5] };
  const float* exp_w[2]  = { (const float*)d_in[6],  (const float*)d_in[10] };
  const float* exp_b[2]  = { (const float*)d_in[7],  (const float*)d_in[11] };
  const float* col_w[2]  = { (const float*)d_in[8],  (const float*)d_in[12] };
  const float* col_b[2]  = { (const float*)d_in[9],  (const float*)d_in[13] };
  const float* gate_w = (const float*)d_in[14];
  const float* gate_b = (const float*)d_in[15];
  const float* ln_g[2] = { (const float*)d_in[16], (const float*)d_in[18] };
  const float* ln_b[2] = { (const float*)d_in[17], (const float*)d_in[19] };
  float* out = (float*)d_out;

  // ---- workspace carve-up (~196.3 MiB peak; lifetime-aliased regions) ----
  char* w = (char*)d_ws;
  auto alloc = [&](size_t bytes) { char* p = w; w += (bytes + 255) & ~(size_t)255; return p; };
  float*          dinv   = (float*)alloc(16384ULL * 4);                     // 64 KiB
  // region A (32 MiB): adj2 [16][1024][1024] bf16; later Gcat [8192][1536] bf16
  char*           regA   = alloc(16ULL * 1024 * 1024 * 2);
  __hip_bfloat16* adj2   = (__hip_bfloat16*)regA;
  __hip_bfloat16* Gcat   = (__hip_bfloat16*)regA;
  __hip_bfloat16* wefft  = (__hip_bfloat16*)alloc(768ULL * 1536 * 2);       // 2.25 MiB
  // region C (24 MiB): bufA2 = AX / T2^T / V   ([16][1024][768] bf16 worth)
  __hip_bfloat16* bufA2  = (__hip_bfloat16*)alloc(16ULL * 1024 * 768 * 2);
  // region D (24 MiB): Xt [8][768][1024] bf16 (first half); later G [16][1024][768]
  char*           regD   = alloc(16ULL * 1024 * 768 * 2);
  __hip_bfloat16* Xt     = (__hip_bfloat16*)regD;
  __hip_bfloat16* bufB2  = (__hip_bfloat16*)regD;
  // region E (96 MiB): X12 = X1 / U, [2][8192][3072] bf16
  __hip_bfloat16* X12    = (__hip_bfloat16*)alloc(2ULL * 8192 * 3072 * 2);
  // regions F/G: w1T/expT and w2T/colT (both graphs; rebuilt mid-stream)
  __hip_bfloat16* wgt1   = (__hip_bfloat16*)alloc(2ULL * 3072 * 768 * 2);   // 9 MiB
  __hip_bfloat16* wgt2   = (__hip_bfloat16*)alloc(2ULL * 768 * 3072 * 2);   // 9 MiB

  const long long sW1 = 3072LL * 768;   // w1T / expT per-graph elems
  const long long sW2 = 768LL * 3072;   // w2T / colT per-graph elems
  const long long sNM = 1024LL * 768;   // per-(g,b) node matrix elems
  const long long sBig = 8192LL * 3072; // per-graph X1/U elems

  // ---- prep ----
  rowsum_dinv<<<4096, 256, 0, stream>>>(graphs, dinv);
  transpose_conv<float><<<dim3(24, 32, 8), dim3(32, 8), 0, stream>>>(
      nodes, Xt, 1024, 768, 1024LL * 768, 768LL * 1024);
  build_wefft<<<4608, 256, 0, stream>>>(gate_w, wefft);
  scale_adj<<<16384, 256, 0, stream>>>(graphs, dinv, adj2);
  for (int g = 0; g < 2; g++) {
    transpose_conv<float><<<dim3(96, 24, 1), dim3(32, 8), 0, stream>>>(
        gcn_w1[g], wgt1 + g * sW1, 768, 3072, 0, 0);
    transpose_conv<float><<<dim3(24, 96, 1), dim3(32, 8), 0, stream>>>(
        gcn_w2[g], wgt2 + g * sW2, 3072, 768, 0, 0);
  }

  // ---- batched pipeline (z = graph*8 + b for per-matrix, z = graph else) ----
  // AX = adj @ X   [1024,1024]@[1024,768] x16  -> bufA2   (Bt = Xt[b], z&7)
  gemm_bt<0, 1, 0><<<dim3(8, 6, 16), 256, 0, stream>>>(
      adj2, 1LL << 20, Xt, 0, sNM, 1024, bufA2, sNM, 768,
      nullptr, nullptr, nullptr, 1024);
  // X1 = relu(AX @ W1)   [8192,768]@[768,3072] x2  -> X12
  gemm_bt<1, 1, 0><<<dim3(64, 24, 2), 256, 0, stream>>>(
      bufA2, 8192LL * 768, wgt1, 0, sW1, 768, X12, sBig, 3072,
      nullptr, nullptr, nullptr, 768);
  // T2^T = (X1 @ W2)^T   [8192,3072]@[3072,768] x2 -> bufA2 as [2][768][8192]
  // (ORIENT=1 fused transpose; AX dead)
  gemm_bt<0, 1, 1><<<dim3(64, 6, 2), 256, 0, stream>>>(
      X12, sBig, wgt2, 0, sW2, 3072, bufA2, 768LL * 8192, 8192,
      nullptr, nullptr, nullptr, 3072);
  // rebuild weight regions with exp/col transposes (w1T/w2T dead)
  for (int g = 0; g < 2; g++) {
    transpose_conv<float><<<dim3(96, 24, 1), dim3(32, 8), 0, stream>>>(
        exp_w[g], wgt1 + g * sW1, 768, 3072, 0, 0);
    transpose_conv<float><<<dim3(24, 96, 1), dim3(32, 8), 0, stream>>>(
        col_w[g], wgt2 + g * sW2, 3072, 768, 0, 0);
  }
  // G = relu(adj @ T2)   [1024,1024]@[1024,768] x16 -> bufB2 (Xt dead)
  // Bt = T2^T: batch offset (z>>3)*768*8192 + (z&7)*1024, row stride 8192
  gemm_bt<1, 1, 0><<<dim3(8, 6, 16), 256, 0, stream>>>(
      adj2, 1LL << 20, bufA2, 768LL * 8192, 1024, 8192, bufB2, sNM, 768,
      nullptr, nullptr, nullptr, 1024);
  // U = gelu(G @ expW + b)   [8192,768]@[768,3072] x2 -> X12 (X1 dead)
  gemm_bt<2, 1, 0><<<dim3(64, 24, 2), 256, 0, stream>>>(
      bufB2, 8192LL * 768, wgt1, 0, sW1, 768, X12, sBig, 3072,
      exp_b[0], exp_b[1], nullptr, 768);
  // V = U @ colW   [8192,3072]@[3072,768] x2 -> bufA2 (T2^T dead)
  gemm_bt<0, 1, 0><<<dim3(64, 6, 2), 256, 0, stream>>>(
      X12, sBig, wgt2, 0, sW2, 3072, bufA2, 8192LL * 768, 768,
      nullptr, nullptr, nullptr, 3072);
  // LN(nodes + V + col_b) both graphs -> Gcat (adj2 dead)
  ln_residual2<<<16384, 256, 0, stream>>>(
      nodes, bufA2, col_b[0], col_b[1], ln_g[0], ln_g[1], ln_b[0], ln_b[1], Gcat);
  // out = sigmoid(Gcat @ WeffT^T + gate_b) blend -> fused gate epilogue
  gemm_bt<3, 0, 0><<<dim3(64, 6, 1), 256, 0, stream>>>(
      Gcat, 0, wefft, 0, 0, 1536, out, 0, 768,
      gate_b, nullptr, Gcat, 1536);
}

// Round 5
// 808.244 us; speedup vs baseline: 1.0717x; 1.0717x over previous
//
#include <hip/hip_runtime.h>
#include <hip/hip_bf16.h>

typedef __bf16 b8v __attribute__((ext_vector_type(8)));
typedef float  f4v __attribute__((ext_vector_type(4)));
typedef unsigned long long ull;

#define AS3(p)  ((__attribute__((address_space(3))) void*)(p))
#define AS1C(p) ((const __attribute__((address_space(1))) void*)(p))

// ============================================================================
// GEMM: C[M,N] = A[M,K] @ Bt[N,K]^T   (A,Bt bf16 K-contig rows, fp32 acc)
// 128x128 tile, BK=32, 256 threads (2x2 waves of 64x64), mfma_f32_16x16x32_bf16
// PIPELINED K-loop: sync_a -> frag reads -> sync_b -> issue loads(it+1) ->
// MFMAs(it).  Next iter's staging overlaps this iter's MFMA block.
// MP: m-tiles per block (serial); tile p+1's first loads issue before tile p's
// epilogue, hiding the per-tile prologue. B-tile L2-hot for p>0.
// Bt batch offset = (z>>3)*sBg + (z&7)*sBb; Bt row stride ldB.
// ORIENT 0: swapped-operand MFMA -> lane holds 4 consecutive COLUMNS of C
//           (row-major C, packed stores).
// ORIENT 1: normal MFMA -> lane holds 4 consecutive ROWS -> writes C^T
//           row-major [N][M] packed (fused transpose).
// EPI: 0 none, 1 relu, 2 bias+gelu (bias by z&1), 3 sigmoid-gate (reads gcat,
//      adds bias0, writes fp32 out = s*g1+(1-s)*g2).  OBF: 1 bf16 out, 0 fp32.
// ============================================================================
template<int EPI, int OBF, int ORIENT, int MP>
__global__ __launch_bounds__(256) void gemm_bt(
    const __hip_bfloat16* __restrict__ A,  long long sA,
    const __hip_bfloat16* __restrict__ Bt, long long sBg, long long sBb, int ldB,
    void* __restrict__ Cv, long long sC, int ldC,
    const float* __restrict__ bias0, const float* __restrict__ bias1,
    const __hip_bfloat16* __restrict__ gcat, int K)
{
  const int bz = blockIdx.z;
  A  += (long long)bz * sA;
  Bt += (long long)(bz >> 3) * sBg + (long long)(bz & 7) * sBb;
  const float* __restrict__ bias = (bz & 1) ? bias1 : bias0;

  __shared__ __hip_bfloat16 As[128 * 32];
  __shared__ __hip_bfloat16 Bs[128 * 32];

  const int tid  = threadIdx.x;
  const int lane = tid & 63;
  const int wave = tid >> 6;

  const long long mBase = (long long)blockIdx.x * (MP * 128);
  const long long n0    = (long long)blockIdx.y * 128;

  // staging: thread t -> tile row r = t>>2, LDS slot t&3 holds global k-cell
  // kc = (t&3)^((r>>2)&3)  (XOR swizzle, cancelled on read)
  const int r  = tid >> 2;
  const int kc = (tid & 3) ^ ((r >> 2) & 3);
  const __hip_bfloat16* aRow = A  + (mBase + r) * (long long)K   + kc * 8;
  const __hip_bfloat16* bRow = Bt + (n0 + r)    * (long long)ldB + kc * 8;

  const int wm = (wave & 1) * 64;
  const int wn = (wave >> 1) * 64;
  const int lm = lane & 15;   // m (A-frag) / n (B-frag) within 16x16 tile
  const int kq = lane >> 4;   // k quad (0..3), 8 elements each

  const int sw   = (lm >> 2) & 3;           // read-side unswizzle
  const int aOff = (wm + lm) * 32 + (kq ^ sw) * 8;
  const int bOff = (wn + lm) * 32 + (kq ^ sw) * 8;

  auto stage = [&](long long aoff, int k0) {
    const __hip_bfloat16* a = aRow + aoff + k0;
    const __hip_bfloat16* b = bRow + k0;
    __builtin_amdgcn_global_load_lds(AS1C(a),              AS3(As + tid * 8),        16, 0, 0);
    __builtin_amdgcn_global_load_lds(AS1C(a + 64LL * K),   AS3(As + 2048 + tid * 8), 16, 0, 0);
    __builtin_amdgcn_global_load_lds(AS1C(b),              AS3(Bs + tid * 8),        16, 0, 0);
    __builtin_amdgcn_global_load_lds(AS1C(b + 64LL * ldB), AS3(Bs + 2048 + tid * 8), 16, 0, 0);
  };

  stage(0, 0);   // prologue: tile 0, k0 = 0

  const f4v fzero = {0.0f, 0.0f, 0.0f, 0.0f};
  char* Cb = (char*)Cv;

  for (int p = 0; p < MP; ++p) {
    const long long aoff = (long long)p * 128 * K;

    f4v acc[4][4];
#pragma unroll
    for (int i = 0; i < 4; i++)
#pragma unroll
      for (int j = 0; j < 4; j++) acc[i][j] = fzero;

    for (int k0 = 0; k0 < K; k0 += 32) {
      __syncthreads();                       // staged (p,k0) resident in LDS

      b8v af[4], bf[4];
#pragma unroll
      for (int i = 0; i < 4; i++) af[i] = *(const b8v*)(As + aOff + i * 16 * 32);
#pragma unroll
      for (int j = 0; j < 4; j++) bf[j] = *(const b8v*)(Bs + bOff + j * 16 * 32);

      __syncthreads();                       // all waves done reading LDS

      if (k0 + 32 < K)            stage(aoff, k0 + 32);          // overlap w/ MFMA
      else if (MP > 1 && p + 1 < MP) stage(aoff + 128LL * K, 0); // next m-tile

#pragma unroll
      for (int i = 0; i < 4; i++)
#pragma unroll
        for (int j = 0; j < 4; j++) {
          if constexpr (ORIENT == 0)
            acc[i][j] = __builtin_amdgcn_mfma_f32_16x16x32_bf16(bf[j], af[i], acc[i][j], 0, 0, 0);
          else
            acc[i][j] = __builtin_amdgcn_mfma_f32_16x16x32_bf16(af[i], bf[j], acc[i][j], 0, 0, 0);
        }
    }

    // ---- epilogue for m-tile p (next tile's loads already in flight) ----
    const long long m0 = mBase + (long long)p * 128;
#pragma unroll
    for (int i = 0; i < 4; i++) {
#pragma unroll
      for (int j = 0; j < 4; j++) {
        float v[4];
#pragma unroll
        for (int rg = 0; rg < 4; rg++) v[rg] = acc[i][j][rg];

        if constexpr (ORIENT == 0) {
          // lane: C row = m0+wm+i*16+lm ; cols = n0+wn+j*16+kq*4 + {0..3}
          const long long row  = m0 + wm + i * 16 + lm;
          const int       colb = (int)n0 + wn + j * 16 + kq * 4;
          if constexpr (EPI == 1) {
#pragma unroll
            for (int rg = 0; rg < 4; rg++) v[rg] = fmaxf(v[rg], 0.0f);
          }
          if constexpr (EPI == 2) {
            const float4 b4 = *(const float4*)(bias + colb);
            const float* bb = (const float*)&b4;
#pragma unroll
            for (int rg = 0; rg < 4; rg++) {
              float x = v[rg] + bb[rg];
              v[rg] = 0.5f * x * (1.0f + erff(x * 0.70710678118654752f));
            }
          }
          const long long base = bz * sC + row * (long long)ldC + colb;
          if constexpr (EPI == 3) {
            const float4 b4 = *(const float4*)(bias0 + colb);
            const float* bb = (const float*)&b4;
            union { __hip_bfloat16 h[4]; ull u; } g1, g2;
            g1.u = *(const ull*)(gcat + row * 1536 + colb);
            g2.u = *(const ull*)(gcat + row * 1536 + 768 + colb);
            float o[4];
#pragma unroll
            for (int rg = 0; rg < 4; rg++) {
              const float s = 1.0f / (1.0f + expf(-(v[rg] + bb[rg])));
              o[rg] = s * __bfloat162float(g1.h[rg]) +
                      (1.0f - s) * __bfloat162float(g2.h[rg]);
            }
            *(float4*)(Cb + base * 4) = *(const float4*)o;
          } else if constexpr (OBF) {
            union { __hip_bfloat16 h[4]; ull u; } P;
#pragma unroll
            for (int rg = 0; rg < 4; rg++) P.h[rg] = __float2bfloat16(v[rg]);
            *(ull*)(Cb + base * 2) = P.u;
          } else {
            *(float4*)(Cb + base * 4) = *(const float4*)v;
          }
        } else {
          // lane: C col(n) = n0+wn+j*16+lm ; rows(m) = m0+wm+i*16+kq*4+{0..3}
          const long long crow = n0 + wn + j * 16 + lm;          // row of C^T
          const long long mb   = m0 + wm + i * 16 + kq * 4;
          if constexpr (EPI == 1) {
#pragma unroll
            for (int rg = 0; rg < 4; rg++) v[rg] = fmaxf(v[rg], 0.0f);
          }
          const long long base = bz * sC + crow * (long long)ldC + mb;
          if constexpr (OBF) {
            union { __hip_bfloat16 h[4]; ull u; } P;
#pragma unroll
            for (int rg = 0; rg < 4; rg++) P.h[rg] = __float2bfloat16(v[rg]);
            *(ull*)(Cb + base * 2) = P.u;
          } else {
            *(float4*)(Cb + base * 4) = *(const float4*)v;
          }
        }
      }
    }
  }
}

// ============================================================================
// adj row-sums -> dinv = 1/sqrt(rowsum).  One wave per row. 16384 rows total.
// ============================================================================
__global__ __launch_bounds__(256) void rowsum_dinv(const float* __restrict__ g,
                                                   float* __restrict__ dinv)
{
  const int wave = threadIdx.x >> 6, lane = threadIdx.x & 63;
  const long long row = (long long)blockIdx.x * 4 + wave;   // [0, 16384)
  const float4* p = (const float4*)(g + row * 1024);
  float s = 0.0f;
#pragma unroll
  for (int k = 0; k < 4; k++) {
    float4 v = p[lane + k * 64];
    s += v.x + v.y + v.z + v.w;
  }
#pragma unroll
  for (int o = 32; o > 0; o >>= 1) s += __shfl_down(s, o);
  if (lane == 0) dinv[row] = 1.0f / sqrtf(s);
}

// ============================================================================
// adj_bf16[g][b][i][j] = graphs[b][g][i][j] * dinv[i] * dinv[j]  (graph-major)
// ============================================================================
__global__ __launch_bounds__(256) void scale_adj(const float* __restrict__ g,
                                                 const float* __restrict__ dinv,
                                                 __hip_bfloat16* __restrict__ out)
{
  const long long t = (long long)blockIdx.x * 256 + threadIdx.x; // quad index
  const long long e = t * 4;
  const int m = (int)(e >> 20);          // b*2+graph (input order)
  const int i = (int)((e >> 10) & 1023);
  const int j = (int)(e & 1023);
  const float4 v  = *(const float4*)(g + e);
  const float  di = dinv[m * 1024 + i];
  const float4 dj = *(const float4*)(dinv + m * 1024 + j);
  const int om = (m & 1) * 8 + (m >> 1); // z = graph*8 + b
  union { __hip_bfloat16 h[4]; ull u; } r;
  r.h[0] = __float2bfloat16(v.x * di * dj.x);
  r.h[1] = __float2bfloat16(v.y * di * dj.y);
  r.h[2] = __float2bfloat16(v.z * di * dj.z);
  r.h[3] = __float2bfloat16(v.w * di * dj.w);
  *(ull*)(out + ((long long)om << 20) + (long long)i * 1024 + j) = r.u;
}

// ============================================================================
// transpose + convert to bf16: out[C,R] = in[R,C], batched via grid.z
// ============================================================================
template<typename TIN>
__global__ void transpose_conv(const TIN* __restrict__ in, __hip_bfloat16* __restrict__ out,
                               int R, int C, long long sIn, long long sOut)
{
  __shared__ __hip_bfloat16 tile[32][33];
  in  += (long long)blockIdx.z * sIn;
  out += (long long)blockIdx.z * sOut;
  const int c0 = blockIdx.x * 32, r0 = blockIdx.y * 32;
  const int tx = threadIdx.x, ty = threadIdx.y;
#pragma unroll
  for (int i = 0; i < 32; i += 8)
    tile[ty + i][tx] = __float2bfloat16((float)in[(long long)(r0 + ty + i) * C + c0 + tx]);
  __syncthreads();
#pragma unroll
  for (int i = 0; i < 32; i += 8)
    out[(long long)(c0 + ty + i) * R + r0 + tx] = tile[tx][ty + i];
}

// ============================================================================
// residual + LayerNorm for BOTH graphs: rows [0,16384), g = row>>13.
// y = LN(nodes + V + col_b) -> bf16 slice of Gcat[r, g*768 : +768].  V bf16.
// ============================================================================
__global__ __launch_bounds__(256) void ln_residual2(
    const float* __restrict__ nodes, const __hip_bfloat16* __restrict__ V,
    const float* __restrict__ colb0, const float* __restrict__ colb1,
    const float* __restrict__ lng0,  const float* __restrict__ lng1,
    const float* __restrict__ lnb0,  const float* __restrict__ lnb1,
    __hip_bfloat16* __restrict__ gcat)
{
  const long long row = blockIdx.x;          // 0..16383
  const int g = (int)(row >> 13);
  const long long rr = row & 8191;           // node row
  const float* __restrict__ colb = g ? colb1 : colb0;
  const float* __restrict__ lng  = g ? lng1  : lng0;
  const float* __restrict__ lnb  = g ? lnb1  : lnb0;
  const int t = threadIdx.x;
  const long long nbase = rr * 768;
  const long long vbase = row * 768;
  float x[3]; float s = 0.0f, ss = 0.0f;
#pragma unroll
  for (int i = 0; i < 3; i++) {
    const int c = t + i * 256;
    const float v = nodes[nbase + c] + __bfloat162float(V[vbase + c]) + colb[c];
    x[i] = v; s += v; ss += v * v;
  }
  __shared__ float red[8];
#pragma unroll
  for (int o = 32; o > 0; o >>= 1) { s += __shfl_down(s, o); ss += __shfl_down(ss, o); }
  const int wave = t >> 6, lane = t & 63;
  if (lane == 0) { red[wave] = s; red[4 + wave] = ss; }
  __syncthreads();
  if (t == 0) {
    red[0] = red[0] + red[1] + red[2] + red[3];
    red[4] = red[4] + red[5] + red[6] + red[7];
  }
  __syncthreads();
  const float mu  = red[0] * (1.0f / 768.0f);
  float var = red[4] * (1.0f / 768.0f) - mu * mu;
  var = fmaxf(var, 0.0f);
  const float rs = rsqrtf(var + 1e-12f);
#pragma unroll
  for (int i = 0; i < 3; i++) {
    const int c = t + i * 256;
    const float y = (x[i] - mu) * rs * lng[c] + lnb[c];
    gcat[rr * 1536 + g * 768 + c] = __float2bfloat16(y);
  }
}

// ============================================================================
// WeffT[n][k] (bf16, [768,1536]): folded gate weight
//   k<768 : (Wa+Wc+Wd)[k][n];  k>=768: (Wb+Wc-Wd)[k-768][n]
// ============================================================================
__global__ __launch_bounds__(256) void build_wefft(const float* __restrict__ gw,
                                                   __hip_bfloat16* __restrict__ wt)
{
  const int idx = blockIdx.x * 256 + threadIdx.x;  // 768*1536, exact
  const int n = idx / 1536, k = idx % 1536;
  float v;
  if (k < 768) v = gw[k * 768 + n] + gw[(1536 + k) * 768 + n] + gw[(2304 + k) * 768 + n];
  else {
    const int kk = k - 768;
    v = gw[(768 + kk) * 768 + n] + gw[(1536 + kk) * 768 + n] - gw[(2304 + kk) * 768 + n];
  }
  wt[idx] = __float2bfloat16(v);
}

// ============================================================================
extern "C" void kernel_launch(void* const* d_in, const int* in_sizes, int n_in,
                              void* d_out, int out_size, void* d_ws, size_t ws_size,
                              hipStream_t stream)
{
  const float* nodes  = (const float*)d_in[0];
  const float* graphs = (const float*)d_in[1];
  const float* gcn_w1[2] = { (const float*)d_in[2], (const float*)d_in[4] };
  const float* gcn_w2[2] = { (const float*)d_in[3], (const float*)d_in[5] };
  const float* exp_w[2]  = { (const float*)d_in[6],  (const float*)d_in[10] };
  const float* exp_b[2]  = { (const float*)d_in[7],  (const float*)d_in[11] };
  const float* col_w[2]  = { (const float*)d_in[8],  (const float*)d_in[12] };
  const float* col_b[2]  = { (const float*)d_in[9],  (const float*)d_in[13] };
  const float* gate_w = (const float*)d_in[14];
  const float* gate_b = (const float*)d_in[15];
  const float* ln_g[2] = { (const float*)d_in[16], (const float*)d_in[18] };
  const float* ln_b[2] = { (const float*)d_in[17], (const float*)d_in[19] };
  float* out = (float*)d_out;

  // ---- workspace carve-up (~196.3 MiB peak; lifetime-aliased regions) ----
  char* w = (char*)d_ws;
  auto alloc = [&](size_t bytes) { char* p = w; w += (bytes + 255) & ~(size_t)255; return p; };
  float*          dinv   = (float*)alloc(16384ULL * 4);                     // 64 KiB
  // region A (32 MiB): adj2 [16][1024][1024] bf16; later Gcat [8192][1536] bf16
  char*           regA   = alloc(16ULL * 1024 * 1024 * 2);
  __hip_bfloat16* adj2   = (__hip_bfloat16*)regA;
  __hip_bfloat16* Gcat   = (__hip_bfloat16*)regA;
  __hip_bfloat16* wefft  = (__hip_bfloat16*)alloc(768ULL * 1536 * 2);       // 2.25 MiB
  // region C (24 MiB): bufA2 = AX / T2^T / V   ([16][1024][768] bf16 worth)
  __hip_bfloat16* bufA2  = (__hip_bfloat16*)alloc(16ULL * 1024 * 768 * 2);
  // region D (24 MiB): Xt [8][768][1024] bf16 (first half); later G [16][1024][768]
  char*           regD   = alloc(16ULL * 1024 * 768 * 2);
  __hip_bfloat16* Xt     = (__hip_bfloat16*)regD;
  __hip_bfloat16* bufB2  = (__hip_bfloat16*)regD;
  // region E (96 MiB): X12 = X1 / U, [2][8192][3072] bf16
  __hip_bfloat16* X12    = (__hip_bfloat16*)alloc(2ULL * 8192 * 3072 * 2);
  // regions F/G: w1T/expT and w2T/colT (both graphs; rebuilt mid-stream)
  __hip_bfloat16* wgt1   = (__hip_bfloat16*)alloc(2ULL * 3072 * 768 * 2);   // 9 MiB
  __hip_bfloat16* wgt2   = (__hip_bfloat16*)alloc(2ULL * 768 * 3072 * 2);   // 9 MiB

  const long long sW1 = 3072LL * 768;   // w1T / expT per-graph elems
  const long long sW2 = 768LL * 3072;   // w2T / colT per-graph elems
  const long long sNM = 1024LL * 768;   // per-(g,b) node matrix elems
  const long long sBig = 8192LL * 3072; // per-graph X1/U elems

  // ---- prep ----
  rowsum_dinv<<<4096, 256, 0, stream>>>(graphs, dinv);
  transpose_conv<float><<<dim3(24, 32, 8), dim3(32, 8), 0, stream>>>(
      nodes, Xt, 1024, 768, 1024LL * 768, 768LL * 1024);
  build_wefft<<<4608, 256, 0, stream>>>(gate_w, wefft);
  scale_adj<<<16384, 256, 0, stream>>>(graphs, dinv, adj2);
  for (int g = 0; g < 2; g++) {
    transpose_conv<float><<<dim3(96, 24, 1), dim3(32, 8), 0, stream>>>(
        gcn_w1[g], wgt1 + g * sW1, 768, 3072, 0, 0);
    transpose_conv<float><<<dim3(24, 96, 1), dim3(32, 8), 0, stream>>>(
        gcn_w2[g], wgt2 + g * sW2, 3072, 768, 0, 0);
  }

  // ---- batched pipeline (z = graph*8 + b for per-matrix, z = graph else) ----
  // AX = adj @ X   [1024,1024]@[1024,768] x16  -> bufA2   (Bt = Xt[b], z&7)
  gemm_bt<0, 1, 0, 1><<<dim3(8, 6, 16), 256, 0, stream>>>(
      adj2, 1LL << 20, Xt, 0, sNM, 1024, bufA2, sNM, 768,
      nullptr, nullptr, nullptr, 1024);
  // X1 = relu(AX @ W1)   [8192,768]@[768,3072] x2  -> X12   (MP=2)
  gemm_bt<1, 1, 0, 2><<<dim3(32, 24, 2), 256, 0, stream>>>(
      bufA2, 8192LL * 768, wgt1, 0, sW1, 768, X12, sBig, 3072,
      nullptr, nullptr, nullptr, 768);
  // T2^T = (X1 @ W2)^T   [8192,3072]@[3072,768] x2 -> bufA2 as [2][768][8192]
  gemm_bt<0, 1, 1, 1><<<dim3(64, 6, 2), 256, 0, stream>>>(
      X12, sBig, wgt2, 0, sW2, 3072, bufA2, 768LL * 8192, 8192,
      nullptr, nullptr, nullptr, 3072);
  // rebuild weight regions with exp/col transposes (w1T/w2T dead)
  for (int g = 0; g < 2; g++) {
    transpose_conv<float><<<dim3(96, 24, 1), dim3(32, 8), 0, stream>>>(
        exp_w[g], wgt1 + g * sW1, 768, 3072, 0, 0);
    transpose_conv<float><<<dim3(24, 96, 1), dim3(32, 8), 0, stream>>>(
        col_w[g], wgt2 + g * sW2, 3072, 768, 0, 0);
  }
  // G = relu(adj @ T2)   [1024,1024]@[1024,768] x16 -> bufB2 (Xt dead)
  // Bt = T2^T: batch offset (z>>3)*768*8192 + (z&7)*1024, row stride 8192
  gemm_bt<1, 1, 0, 1><<<dim3(8, 6, 16), 256, 0, stream>>>(
      adj2, 1LL << 20, bufA2, 768LL * 8192, 1024, 8192, bufB2, sNM, 768,
      nullptr, nullptr, nullptr, 1024);
  // U = gelu(G @ expW + b)   [8192,768]@[768,3072] x2 -> X12 (X1 dead)  (MP=2)
  gemm_bt<2, 1, 0, 2><<<dim3(32, 24, 2), 256, 0, stream>>>(
      bufB2, 8192LL * 768, wgt1, 0, sW1, 768, X12, sBig, 3072,
      exp_b[0], exp_b[1], nullptr, 768);
  // V = U @ colW   [8192,3072]@[3072,768] x2 -> bufA2 (T2^T dead)
  gemm_bt<0, 1, 0, 1><<<dim3(64, 6, 2), 256, 0, stream>>>(
      X12, sBig, wgt2, 0, sW2, 3072, bufA2, 8192LL * 768, 768,
      nullptr, nullptr, nullptr, 3072);
  // LN(nodes + V + col_b) both graphs -> Gcat (adj2 dead)
  ln_residual2<<<16384, 256, 0, stream>>>(
      nodes, bufA2, col_b[0], col_b[1], ln_g[0], ln_g[1], ln_b[0], ln_b[1], Gcat);
  // out = sigmoid(Gcat @ WeffT^T + gate_b) blend -> fused gate epilogue
  gemm_bt<3, 0, 0, 1><<<dim3(64, 6, 1), 256, 0, stream>>>(
      Gcat, 0, wefft, 0, 0, 1536, out, 0, 768,
      gate_b, nullptr, Gcat, 1536);
}